// Round 4
// baseline (345.591 us; speedup 1.0000x reference)
//
#include <hip/hip_runtime.h>

#define NBATCH 4
#define NPTS   16384
#define NQ     4096
#define NCH    64
#define K      32
#define CHOUT  67   // 3 + NCH

typedef float v2f __attribute__((ext_vector_type(2)));
typedef float v4f __attribute__((ext_vector_type(4)));
typedef int   v4i __attribute__((ext_vector_type(4)));

// Packed fp32 ops via asm: exact rn rounding, no contraction possible.
__device__ __forceinline__ v2f pk_add(v2f a, v2f b) {
    v2f d; asm("v_pk_add_f32 %0, %1, %2" : "=v"(d) : "v"(a), "v"(b)); return d;
}
__device__ __forceinline__ v2f pk_mul(v2f a, v2f b) {
    v2f d; asm("v_pk_mul_f32 %0, %1, %2" : "=v"(d) : "v"(a), "v"(b)); return d;
}
// FMA variant: used ONLY in pass 1 (threshold estimate), never for the exact
// pass-2 distances that determine selection/ordering.
__device__ __forceinline__ v2f pk_fma(v2f a, v2f b, v2f c) {
    v2f d; asm("v_pk_fma_f32 %0, %1, %2, %3" : "=v"(d) : "v"(a), "v"(b), "v"(c)); return d;
}
// Whole-wave shift lane i -> i+1 (DPP wave_shr:1, ctrl 0x138). Lane 0 keeps old.
__device__ __forceinline__ int dpp_shr1(int v) {
    return __builtin_amdgcn_update_dpp(v, v, 0x138, 0xf, 0xf, false);
}
// Per-lane select on an arbitrary 64-bit lane mask held in SGPRs: m ? t : f.
__device__ __forceinline__ int sel_mask_i(unsigned long long m, int t, int f) {
    int d; asm("v_cndmask_b32 %0, %2, %1, %3" : "=v"(d) : "v"(t), "v"(f), "s"(m));
    return d;
}

// ---------------------------------------------------------------------------
// R10: knn is VALU-ISSUE bound (time invariant across occupancy/LDS/async
// changes; VALUBusy ~65%). Cut issued instructions:
//  - SoA x,y,z,|p|^2 staged per-comp -> ONE vaddr + immediate-offset LDS reads.
//  - Pass 1 uses s = |p|^2 - 2 p.q (3 pk_fma vs 8 ops); |q|^2 shift is
//    rank-invariant per query. Threshold moves to d-domain with absolute
//    slack 1e-2 >> 1e-4 error bound -> pass-2 filter provably complete.
//  - Radix descent on sign-corrected uint encoding (s may be negative).
// Pass 2 exact math / merge order / sorted insert: bit-identical to R6/R9.
// ---------------------------------------------------------------------------
constexpr int TILE = 512;           // points per tile
constexpr int NT   = NPTS / TILE;   // 32 tiles per pass
constexpr int QPW  = 4;
constexpr int QPB  = 16;            // 4 waves x QPW

#define VW2 asm volatile("s_waitcnt vmcnt(2)" ::: "memory")
#define VW0 asm volatile("s_waitcnt vmcnt(0)" ::: "memory")
#define BAR __builtin_amdgcn_s_barrier()

template <bool FUSED>
__global__ __launch_bounds__(256) void knn_kernel(
    const float* __restrict__ xn,     // SoA per batch: x[16384] y z n2
    const float* __restrict__ xyz,    // original AoS, for epilogue coords
    const float* __restrict__ new_xyz,
    const float* __restrict__ ft,     // featT (B,N,C); used when FUSED
    int*   __restrict__ out_idx,      // used when !FUSED
    float* __restrict__ out)
{
    // ring-3 x 4 comps x 512 pts = 24 KB
    __shared__ __align__(16) float sb[3][4][TILE];

    const int tid  = threadIdx.x;
    const int lane = tid & 63;
    const int wave = tid >> 6;
    const int b    = blockIdx.x >> 8;                  // 256 blocks per batch
    const int q0   = (blockIdx.x & 255) * QPB + wave * QPW;

    const float* xb  = xyz + (size_t)b * NPTS * 3;
    const float* xnb = xn + (size_t)b * 4 * NPTS;
    // wave w stages comp w: per tile 512 floats = 2 x (64 lanes x 16 B).
    const char* gbase = (const char*)(xnb + (size_t)wave * NPTS) + lane * 16;

    // offset=0 ONLY (global_load_lds applies imm offset to BOTH addresses).
    auto STAGE = [&](int buf, int t0) {
        const char* g = gbase + (size_t)t0 * 4;
        char* l = (char*)(&sb[buf][wave][0]);
#define GLL(k) __builtin_amdgcn_global_load_lds( \
        (const __attribute__((address_space(1))) unsigned int*)(g + (k) * 1024), \
        (__attribute__((address_space(3))) unsigned int*)(l + (k) * 1024), \
        16, 0, 0)
        GLL(0); GLL(1);
#undef GLL
    };

    // Query scalars (wave-uniform -> SGPR). nq = -q ; m2q = -2q ; q2 = |q|^2.
    float nqx[QPW], nqy[QPW], nqz[QPW], q2s[QPW];
    v2f nqx2[QPW], nqy2[QPW], nqz2[QPW];
    v2f m2x2[QPW], m2y2[QPW], m2z2[QPW];
#pragma unroll
    for (int j = 0; j < QPW; ++j) {
        const int base = ((b * NQ) + q0 + j) * 3;
        nqx[j] = __int_as_float(__builtin_amdgcn_readfirstlane(__float_as_int(-new_xyz[base + 0])));
        nqy[j] = __int_as_float(__builtin_amdgcn_readfirstlane(__float_as_int(-new_xyz[base + 1])));
        nqz[j] = __int_as_float(__builtin_amdgcn_readfirstlane(__float_as_int(-new_xyz[base + 2])));
        nqx2[j] = (v2f){nqx[j], nqx[j]};
        nqy2[j] = (v2f){nqy[j], nqy[j]};
        nqz2[j] = (v2f){nqz[j], nqz[j]};
        const float m2x = nqx[j] + nqx[j];   // -2q, exact (x2)
        const float m2y = nqy[j] + nqy[j];
        const float m2z = nqz[j] + nqz[j];
        m2x2[j] = (v2f){m2x, m2x};
        m2y2[j] = (v2f){m2y, m2y};
        m2z2[j] = (v2f){m2z, m2z};
        q2s[j] = nqx[j] * nqx[j] + nqy[j] * nqy[j] + nqz[j] * nqz[j];
    }

    const float INF  = __int_as_float(0x7f800000);
    const float NINF = __int_as_float(0xff800000);

    // ---------------- Pass 1: per-lane minima of s = |p|^2 - 2p.q ----------
    float vmA[QPW], vmB[QPW];
#pragma unroll
    for (int j = 0; j < QPW; ++j) { vmA[j] = INF; vmB[j] = INF; }

    STAGE(0, 0);
    STAGE(1, TILE);
    VW2; BAR;
    {
        int cur = 0, pre = 2;
        for (int t = 0; t < NT; ++t) {
            if (t + 2 < NT) STAGE(pre, (t + 2) * TILE);
            const float* sp = &sb[cur][0][0];
#pragma unroll
            for (int ii = 0; ii < TILE / 128; ++ii) {     // 4
                // lane owns points (base+2*lane, base+2*lane+1); one vaddr,
                // comp strides are compile-time immediates.
                const float* qp = sp + ii * 128 + 2 * lane;
                const v2f x2  = *(const v2f*)(qp);
                const v2f y2  = *(const v2f*)(qp + TILE);
                const v2f z2  = *(const v2f*)(qp + 2 * TILE);
                const v2f n22 = *(const v2f*)(qp + 3 * TILE);
#pragma unroll
                for (int j = 0; j < QPW; ++j) {
                    v2f s = pk_fma(z2, m2z2[j], n22);
                    s = pk_fma(y2, m2y2[j], s);
                    s = pk_fma(x2, m2x2[j], s);
                    vmA[j] = fminf(vmA[j], s.x);
                    vmB[j] = fminf(vmB[j], s.y);
                }
            }
            if (t + 1 < NT) {
                if (t + 2 < NT) { VW2; } else { VW0; }
                BAR;
            }
            cur = (cur == 2) ? 0 : cur + 1;
            pre = (pre == 2) ? 0 : pre + 1;
        }
    }
    BAR;   // all waves done reading sb before pass-2 prologue overwrites it

    // Pass-2 prologue staging overlaps the radix descent.
    STAGE(0, 0);
    STAGE(1, TILE);

    // -------- T' : exact 32nd smallest lane-min of s (signed-safe) ---------
    // Then Tf = Ts + |q|^2 + 0.01 in d-domain: absolute slack 1e-2 covers the
    // fma/cancellation error (<~1e-4 for |coord|<=8) with ~100x margin, so
    // every true top-32 point passes the exact-d2 filter below.
    float Tf[QPW];
#pragma unroll
    for (int j = 0; j < QPW; ++j) {
        const unsigned bits = __float_as_uint(fminf(vmA[j], vmB[j]));
        // order-preserving float->uint (handles negatives)
        const unsigned u = bits ^ ((((unsigned)(((int)bits) >> 31)) >> 1) | 0x80000000u);
        unsigned t = 0xFFFFFFFFu;
        for (int bb = 31; bb >= 0; --bb) {
            const unsigned tt = t ^ (1u << bb);
            const int cnt = __popcll(__ballot(u <= tt));
            if (cnt >= 32) t = tt;                      // s_cselect, branchless
        }
        const unsigned fb2 = (t & 0x80000000u) ? (t ^ 0x80000000u) : ~t;
        const float Ts = __uint_as_float(fb2);
        Tf[j] = __fadd_rn(__fadd_rn(Ts, q2s[j]), 0.01f);
    }

    // ---------------- Pass 2: filtered exact selection (rn-exact) ----------
    float ld[QPW]; int li[QPW];
#pragma unroll
    for (int j = 0; j < QPW; ++j) {
        ld[j] = (lane < K) ? INF : NINF;   // -inf sentinel: lanes 32+ never shift
        li[j] = 0;
    }

    VW2; BAR;
    {
        int cur = 0, pre = 2;
        for (int t = 0; t < NT; ++t) {
            if (t + 2 < NT) STAGE(pre, (t + 2) * TILE);
            const int t0 = t * TILE;
            const float* sp = &sb[cur][0][0];
#pragma unroll
            for (int ii = 0; ii < TILE / 128; ++ii) {
                const int gb = t0 + ii * 128;              // wave-uniform
                const float* qp = sp + ii * 128 + 2 * lane;
                const v2f x2 = *(const v2f*)(qp);
                const v2f y2 = *(const v2f*)(qp + TILE);
                const v2f z2 = *(const v2f*)(qp + 2 * TILE);
#pragma unroll
                for (int j = 0; j < QPW; ++j) {
                    const v2f dx = pk_add(x2, nqx2[j]);
                    const v2f dy = pk_add(y2, nqy2[j]);
                    const v2f dz = pk_add(z2, nqz2[j]);
                    const v2f d2 = pk_add(pk_add(pk_mul(dx, dx), pk_mul(dy, dy)),
                                          pk_mul(dz, dz));
                    unsigned long long m0 = __ballot(d2.x <= Tf[j]);
                    unsigned long long m1 = __ballot(d2.y <= Tf[j]);
                    // lane c owns indices gb+2c (m0) and gb+2c+1 (m1);
                    // merge by ascending global index: 2c0 vs 2c1+1.
                    while (m0 | m1) {
                        const int c0 = m0 ? (int)__builtin_ctzll(m0) : 64;
                        const int c1 = m1 ? (int)__builtin_ctzll(m1) : 64;
                        const bool lo = c0 <= c1;
                        const int c = lo ? c0 : c1;
                        if (lo) m0 &= m0 - 1; else m1 &= m1 - 1;
                        const int b0 = __builtin_amdgcn_readlane(__float_as_int(d2.x), c);
                        const int b1 = __builtin_amdgcn_readlane(__float_as_int(d2.y), c);
                        const float dn = __int_as_float(lo ? b0 : b1);
                        const int cand = gb + 2 * c + (lo ? 0 : 1);
                        // Self-guarding sorted insert (no-op if dn >= current max).
                        const unsigned long long sh = __ballot(ld[j] > dn);
                        const int p = sh ? (int)__builtin_ctzll(sh) : 64;
                        const int sld = dpp_shr1(__float_as_int(ld[j]));
                        const int sli = dpp_shr1(li[j]);
                        const int nld = sel_mask_i(sh, sld, __float_as_int(ld[j]));
                        const int nli = sel_mask_i(sh, sli, li[j]);
                        ld[j] = __int_as_float((lane == p) ? __float_as_int(dn) : nld);
                        li[j] = (lane == p) ? cand : nli;
                    }
                }
            }
            if (t + 1 < NT) {
                if (t + 2 < NT) { VW2; } else { VW0; }
                BAR;
            }
            cur = (cur == 2) ? 0 : cur + 1;
            pre = (pre == 2) ? 0 : pre + 1;
        }
    }

    // ---------------- Epilogue ----------------
    const size_t plane = (size_t)NQ * K;
#pragma unroll
    for (int j = 0; j < QPW; ++j) {
        const int q = q0 + j;
        if (lane < K) {
            const int idx = li[j];
            const float px = xb[idx * 3 + 0];
            const float py = xb[idx * 3 + 1];
            const float pz = xb[idx * 3 + 2];
            const size_t o = (((size_t)b * CHOUT + 0) * NQ + q) * K + lane;
            out[o]             = __fadd_rn(px, nqx[j]);   // == px - qx, exact
            out[o + plane]     = __fadd_rn(py, nqy[j]);
            out[o + 2 * plane] = __fadd_rn(pz, nqz[j]);
        }
        if (FUSED) {
            // feature channels 3..66: lane (s,h) pulls half-row h (128 B) of
            // point li[j]@lane s, scatters per-channel (32-lane chunks).
            const int s = lane & 31, h = lane >> 5;
            const int pidx = __shfl(li[j], s);
            const v4f* src = (const v4f*)(ft + ((size_t)b * NPTS + pidx) * NCH) + h * 8;
            v4f r[8];
#pragma unroll
            for (int k2 = 0; k2 < 8; ++k2) r[k2] = src[k2];
            float* ob = out + (((size_t)b * CHOUT + 3) * NQ + q) * K + s;
#pragma unroll
            for (int k2 = 0; k2 < 8; ++k2) {
                const int c0 = h * 32 + k2 * 4;
                ob[(size_t)(c0 + 0) * plane] = r[k2].x;
                ob[(size_t)(c0 + 1) * plane] = r[k2].y;
                ob[(size_t)(c0 + 2) * plane] = r[k2].z;
                ob[(size_t)(c0 + 3) * plane] = r[k2].w;
            }
        } else if (lane < K) {
            out_idx[((size_t)(b * NQ) + q) * K + lane] = li[j];
        }
    }
}

// ---------------------------------------------------------------------------
// Kernel P: xyz (B,N,3) -> SoA x,y,z,|p|^2 per batch (1 MB). ~2 us.
// ---------------------------------------------------------------------------
__global__ __launch_bounds__(256) void xyzn_kernel(
    const float* __restrict__ xyz, float* __restrict__ xn)
{
    const int g = blockIdx.x * 256 + threadIdx.x;      // B*NPTS threads
    const int b = g >> 14, n = g & (NPTS - 1);
    const float x = xyz[(size_t)g * 3 + 0];
    const float y = xyz[(size_t)g * 3 + 1];
    const float z = xyz[(size_t)g * 3 + 2];
    float* o = xn + (size_t)b * 4 * NPTS + n;
    o[0]            = x;
    o[NPTS]         = y;
    o[2 * NPTS]     = z;
    o[3 * NPTS]     = __fmaf_rn(z, z, __fmaf_rn(y, y, x * x));
}

// ---------------------------------------------------------------------------
// Kernel T (R10 rewrite): features (B,C,N) -> featT (B,N,C).
// 64n x 64c tiles; v4f global loads (1 KB/wave-instr over 4 rows), LDS
// [n][65] (2-way free both sides), v4f global stores. grid B*256 = 1024.
// Old dword version measured ~115 us (0.29 TB/s) -- the hidden hog.
// ---------------------------------------------------------------------------
__global__ __launch_bounds__(256) void transpose_kernel(
    const float* __restrict__ f, float* __restrict__ ft)
{
    __shared__ float sm[64][65];   // 16.6 KB
    const int tid = threadIdx.x;
    const int nb  = blockIdx.x & 255;         // NPTS/64 tiles
    const int b   = blockIdx.x >> 8;
    const int n0  = nb * 64;
    const int w = tid >> 6, lane = tid & 63;
    const int r = lane >> 4, i = lane & 15;
    const float* fb = f + (size_t)b * NCH * NPTS;
#pragma unroll
    for (int g = 0; g < 4; ++g) {             // channels g*16 + w*4 + r
        const int c = g * 16 + w * 4 + r;
        const v4f v = *(const v4f*)(fb + (size_t)c * NPTS + n0 + 4 * i);
        sm[4 * i + 0][c] = v.x;
        sm[4 * i + 1][c] = v.y;
        sm[4 * i + 2][c] = v.z;
        sm[4 * i + 3][c] = v.w;
    }
    __syncthreads();
    float* ftb = ft + ((size_t)b * NPTS + n0) * NCH;
#pragma unroll
    for (int h = 0; h < 4; ++h) {             // rows n = h*16 + w*4 + r
        const int n = h * 16 + w * 4 + r;
        *(v4f*)(ftb + (size_t)n * NCH + 4 * i) = *(const v4f*)(&sm[n][4 * i]);
    }
}

// ---------------------------------------------------------------------------
// Fallback gather (R6 path) in case ws_size cannot hold featT.
// ---------------------------------------------------------------------------
__global__ __launch_bounds__(1024) void gather_kernel(
    const float* __restrict__ features,
    const int*   __restrict__ idx,
    float* __restrict__ out)
{
    __shared__ __align__(16) float row[NPTS];   // 64 KB

    const int tid  = threadIdx.x;
    const int half = blockIdx.x & 1;
    const int c    = (blockIdx.x >> 1) & 63;
    const int b    = blockIdx.x >> 7;

    const v4f* src = (const v4f*)(features + ((size_t)(b * NCH + c)) * NPTS);
    for (int k2 = tid; k2 < NPTS / 4; k2 += 1024) ((v4f*)row)[k2] = src[k2];
    __syncthreads();

    const size_t hofs = (size_t)half * (NQ * K / 2);
    const v4i* gi = (const v4i*)(idx + (size_t)b * NQ * K + hofs);
    v4f* dst = (v4f*)(out + ((size_t)(b * CHOUT + 3 + c)) * NQ * K + hofs);

    v4i cur = gi[tid];
#pragma unroll
    for (int it = 0; it < 16; ++it) {                  // NQ*K/8/1024 = 16
        v4i nxt;
        if (it < 15) nxt = gi[tid + (it + 1) * 1024];
        v4f o;
        o.x = row[cur.x]; o.y = row[cur.y]; o.z = row[cur.z]; o.w = row[cur.w];
        dst[tid + it * 1024] = o;
        cur = nxt;
    }
}

extern "C" void kernel_launch(void* const* d_in, const int* in_sizes, int n_in,
                              void* d_out, int out_size, void* d_ws, size_t ws_size,
                              hipStream_t stream) {
    const float* xyz      = (const float*)d_in[0];
    const float* new_xyz  = (const float*)d_in[1];
    const float* features = (const float*)d_in[2];
    float* out = (float*)d_out;

    const size_t ft_bytes  = (size_t)NBATCH * NPTS * NCH * sizeof(float);  // 16.8 MB
    const size_t xn_bytes  = (size_t)NBATCH * 4 * NPTS * sizeof(float);    // 1 MB
    const size_t idx_bytes = (size_t)NBATCH * NQ * K * sizeof(int);        // 2 MB

    if (ws_size >= ft_bytes + xn_bytes) {
        float* featT = (float*)d_ws;
        float* xn    = (float*)((char*)d_ws + ft_bytes);
        xyzn_kernel<<<dim3(NBATCH * NPTS / 256), dim3(256), 0, stream>>>(xyz, xn);
        transpose_kernel<<<dim3(NBATCH * (NPTS / 64)), dim3(256), 0, stream>>>(features, featT);
        knn_kernel<true><<<dim3(NBATCH * (NQ / QPB)), dim3(256), 0, stream>>>(
            xn, xyz, new_xyz, featT, nullptr, out);
    } else {
        int*   ws_idx = (int*)d_ws;                                   // 2 MB
        float* xn     = (float*)((char*)d_ws + idx_bytes);            // 1 MB
        xyzn_kernel<<<dim3(NBATCH * NPTS / 256), dim3(256), 0, stream>>>(xyz, xn);
        knn_kernel<false><<<dim3(NBATCH * (NQ / QPB)), dim3(256), 0, stream>>>(
            xn, xyz, new_xyz, nullptr, ws_idx, out);
        gather_kernel<<<dim3(NBATCH * NCH * 2), dim3(1024), 0, stream>>>(features, ws_idx, out);
    }
}